// Round 14
// baseline (943.657 us; speedup 1.0000x reference)
//
#include <hip/hip_runtime.h>
#include <cstdint>
#include <cstddef>

#define L_C   2048
#define DIMC  5120
#define HD    128
#define NHEADS 40

typedef __bf16 bf16_t;
typedef __bf16 bf16x8 __attribute__((ext_vector_type(8)));
typedef __bf16 bf16x4 __attribute__((ext_vector_type(4)));
typedef float  f32x4  __attribute__((ext_vector_type(4)));

#define MFMA16(A,B,C) __builtin_amdgcn_mfma_f32_16x16x32_bf16((A),(B),(C),0,0,0)
#define BARRIER() __builtin_amdgcn_s_barrier()
#define LGKM0()  asm volatile("s_waitcnt lgkmcnt(0)" ::: "memory")
#define VMCNT0() asm volatile("s_waitcnt vmcnt(0)" ::: "memory")
#define VMCNT4() asm volatile("s_waitcnt vmcnt(4)" ::: "memory")
#define VMCNT6() asm volatile("s_waitcnt vmcnt(6)" ::: "memory")
#define VMCNT8() asm volatile("s_waitcnt vmcnt(8)" ::: "memory")

__device__ __forceinline__ void gload16(const void* g, void* l) {
  __builtin_amdgcn_global_load_lds(
      (__attribute__((address_space(1))) void*)(void*)g,
      (__attribute__((address_space(3))) void*)l, 16, 0, 0);
}

// ======== prep: wtrans(Wqkv) [0,19200) | X convert [19200,21248) ========
__global__ __launch_bounds__(256) void prep_all(const float* __restrict__ hidden,
                                                bf16_t* __restrict__ X,
                                                const float* __restrict__ Wqkv,
                                                bf16_t* __restrict__ WQT) {
  __shared__ bf16_t t[64 * 68];
  const int tid = threadIdx.x;
  int bid = blockIdx.x;
  if (bid >= 19200) {
    size_t i = (size_t)(bid - 19200) * 256 + tid;
    const size_t n8 = (size_t)L_C * DIMC / 8;
    const size_t stride = (size_t)2048 * 256;
    for (; i < n8; i += stride) {
      f32x4 a = *(const f32x4*)(hidden + i * 8);
      f32x4 b = *(const f32x4*)(hidden + i * 8 + 4);
      bf16x8 o;
#pragma unroll
      for (int j = 0; j < 4; ++j) { o[j] = (bf16_t)a[j]; o[4 + j] = (bf16_t)b[j]; }
      *(bf16x8*)(X + i * 8) = o;
    }
    return;
  }
  const int K = DIMC, N = 3 * DIMC;
  const int k0 = (bid % 80) * 64, n0 = (bid / 80) * 64;
  const int tn = tid & 15, tk = tid >> 4;
  f32x4 v[4];
#pragma unroll
  for (int jj = 0; jj < 4; ++jj)
    v[jj] = *(const f32x4*)(Wqkv + (size_t)(k0 + 4 * tk + jj) * N + n0 + 4 * tn);
#pragma unroll
  for (int j = 0; j < 4; ++j) {
    bf16x4 o;
#pragma unroll
    for (int jj = 0; jj < 4; ++jj) o[jj] = (bf16_t)v[jj][j];
    *(bf16x4*)&t[(4 * tn + j) * 68 + 4 * tk] = o;
  }
  __syncthreads();
#pragma unroll
  for (int i = 0; i < 2; ++i) {
    int c = i * 256 + tid, rn = c >> 3, ck = (c & 7) * 8;
    bf16x8 o = *(const bf16x8*)&t[rn * 68 + ck];
    *(bf16x8*)(WQT + (size_t)(n0 + rn) * K + k0 + ck) = o;
  }
}

// ======== merged post-QKV: norm_rope [0,2048) | v_trans [2048,3328) ========
__global__ __launch_bounds__(256) void post_qkv(const bf16_t* __restrict__ qkv,
                                                const float* __restrict__ wq,
                                                const float* __restrict__ wk,
                                                const float* __restrict__ fcos,
                                                const float* __restrict__ fsin,
                                                bf16_t* __restrict__ Qo,
                                                bf16_t* __restrict__ Ko,
                                                bf16_t* __restrict__ Vt) {
  __shared__ __align__(16) char sbuf[20992];
  const int tid = threadIdx.x;
  if (blockIdx.x >= 2048) {
    bf16_t* t = (bf16_t*)sbuf;  // [128][68]
    const int idx = blockIdx.x - 2048;
    const int l0 = (idx & 31) * 64, h = idx >> 5;
    const int td = tid & 31, tl = tid >> 5;
#pragma unroll
    for (int it = 0; it < 2; ++it) {
      const int lq = tl + it * 8;
      bf16x4 v[4];
#pragma unroll
      for (int jj = 0; jj < 4; ++jj)
        v[jj] = *(const bf16x4*)(qkv + (size_t)(l0 + 4 * lq + jj) * (3 * DIMC) +
                                 2 * DIMC + h * HD + 4 * td);
#pragma unroll
      for (int j = 0; j < 4; ++j) {
        bf16x4 o;
#pragma unroll
        for (int jj = 0; jj < 4; ++jj) o[jj] = v[jj][j];
        *(bf16x4*)&t[(4 * td + j) * 68 + 4 * lq] = o;
      }
    }
    __syncthreads();
#pragma unroll
    for (int i = 0; i < 4; ++i) {
      int c = i * 256 + tid, d = c >> 3, cl = (c & 7) * 8;
      bf16x8 o = *(const bf16x8*)&t[d * 68 + cl];
      *(bf16x8*)(Vt + ((size_t)h * HD + d) * L_C + l0 + cl) = o;
    }
    return;
  }
  bf16_t* qs  = (bf16_t*)sbuf;
  bf16_t* ks_ = (bf16_t*)(sbuf + 10240);
  float*  red = (float*)(sbuf + 20480);
  const int l = blockIdx.x;
  const bf16_t* row = qkv + (size_t)l * (3 * DIMC);
  float sq = 0.f, sk = 0.f;
  for (int i = tid; i < DIMC / 8; i += 256) {
    bf16x8 a = *(const bf16x8*)(row + i * 8);
    bf16x8 b = *(const bf16x8*)(row + DIMC + i * 8);
    *(bf16x8*)&qs[i * 8] = a;
    *(bf16x8*)&ks_[i * 8] = b;
#pragma unroll
    for (int j = 0; j < 8; ++j) {
      float x = (float)a[j]; sq += x * x;
      float y = (float)b[j]; sk += y * y;
    }
  }
#pragma unroll
  for (int off = 32; off; off >>= 1) {
    sq += __shfl_xor(sq, off, 64);
    sk += __shfl_xor(sk, off, 64);
  }
  const int wid = tid >> 6, lane = tid & 63;
  if (!lane) { red[wid] = sq; red[4 + wid] = sk; }
  __syncthreads();
  sq = red[0] + red[1] + red[2] + red[3];
  sk = red[4] + red[5] + red[6] + red[7];
  const float rq = rsqrtf(sq * (1.f / DIMC) + 1e-6f);
  const float rk = rsqrtf(sk * (1.f / DIMC) + 1e-6f);
  for (int i = tid; i < DIMC / 8; i += 256) {
    const int j0 = i * 8, h = j0 >> 7, d0 = j0 & 127;
    bf16x8 a = *(const bf16x8*)&qs[j0];
    bf16x8 b = *(const bf16x8*)&ks_[j0];
    f32x4 cA = *(const f32x4*)(fcos + (size_t)l * HD + d0);
    f32x4 cB = *(const f32x4*)(fcos + (size_t)l * HD + d0 + 4);
    f32x4 sA = *(const f32x4*)(fsin + (size_t)l * HD + d0);
    f32x4 sB = *(const f32x4*)(fsin + (size_t)l * HD + d0 + 4);
    f32x4 wqA = *(const f32x4*)(wq + j0), wqB = *(const f32x4*)(wq + j0 + 4);
    f32x4 wkA = *(const f32x4*)(wk + j0), wkB = *(const f32x4*)(wk + j0 + 4);
    float cc[8], ss[8], qn[8], kn[8];
#pragma unroll
    for (int j = 0; j < 4; ++j) {
      cc[j] = cA[j]; cc[4 + j] = cB[j];
      ss[j] = sA[j]; ss[4 + j] = sB[j];
      qn[j] = (float)a[j] * rq * wqA[j];
      qn[4 + j] = (float)a[4 + j] * rq * wqB[j];
      kn[j] = (float)b[j] * rk * wkA[j];
      kn[4 + j] = (float)b[4 + j] * rk * wkB[j];
    }
    bf16x8 oq, ok;
#pragma unroll
    for (int p = 0; p < 4; ++p) {
      const float c = cc[2 * p], s = ss[2 * p + 1];
      oq[2 * p]     = (bf16_t)(qn[2 * p] * c - qn[2 * p + 1] * s);
      oq[2 * p + 1] = (bf16_t)(qn[2 * p] * s + qn[2 * p + 1] * c);
      ok[2 * p]     = (bf16_t)(kn[2 * p] * c - kn[2 * p + 1] * s);
      ok[2 * p + 1] = (bf16_t)(kn[2 * p] * s + kn[2 * p + 1] * c);
    }
    *(bf16x8*)(Qo + ((size_t)h * L_C + l) * HD + d0) = oq;
    *(bf16x8*)(Ko + ((size_t)h * L_C + l) * HD + d0) = ok;
  }
}

// ================= 256x256 GEMM, fine-interleaved 8-phase (round-7 verified) =================
template <int OUT_BF16, int K>
__global__ __launch_bounds__(512, 1) void gemm8(const bf16_t* __restrict__ A,
                                                const bf16_t* __restrict__ Bt,
                                                const float* __restrict__ bias,
                                                bf16_t* __restrict__ Cb,
                                                float* __restrict__ Cf,
                                                int M, int N) {
  __shared__ __align__(16) char smem[131072];
  const int tid = threadIdx.x;
  const int wid = tid >> 6, lane = tid & 63;
  const int g = lane >> 4, r = lane & 15;
  const int wm = wid >> 2, wn = wid & 3;
  const int nb = gridDim.x * gridDim.y;
  const int bid = blockIdx.y * gridDim.x + blockIdx.x;
  const int swz = (bid & 7) * (nb >> 3) + (bid >> 3);
  const int bm = swz % gridDim.x, bn = swz / gridDim.x;
  const int row0 = bm * 256, col0 = bn * 256;

  auto stageA = [&](int buf, int half, int kt) {
#pragma unroll
    for (int i = 0; i < 2; ++i) {
      const int idx = i * 512 + tid;
      const int rl = idx >> 3, c = idx & 7;
      gload16(A + (size_t)(row0 + half * 128 + rl) * K + kt * 64 + ((c ^ (rl & 7)) << 3),
              smem + buf * 65536 + half * 16384 + (i * 512 + wid * 64) * 16);
    }
  };
  auto stageB = [&](int buf, int half, int kt) {
#pragma unroll
    for (int i = 0; i < 2; ++i) {
      const int idx = i * 512 + tid;
      const int rl = idx >> 3, c = idx & 7;
      gload16(Bt + (size_t)(col0 + half * 128 + rl) * K + kt * 64 + ((c ^ (rl & 7)) << 3),
              smem + buf * 65536 + 32768 + half * 16384 + (i * 512 + wid * 64) * 16);
    }
  };
  auto ldA = [&](int buf, int mi, int kk) {
    const int rh = mi * 16 + r;
    return *(const bf16x8*)(smem + buf * 65536 + wm * 16384 + rh * 128 +
                            (((kk * 4 + g) ^ (r & 7)) << 4));
  };
  auto ldB = [&](int buf, int ni, int kk) {
    const int rh = (wn & 1) * 64 + ni * 16 + r;
    return *(const bf16x8*)(smem + buf * 65536 + 32768 + (wn >> 1) * 16384 + rh * 128 +
                            (((kk * 4 + g) ^ (r & 7)) << 4));
  };

  f32x4 acc[8][4] = {};
  bf16x8 af[4][2], bfr[4][2];
  constexpr int nk = K / 64;

  stageA(0, 0, 0); stageA(0, 1, 0); stageB(0, 0, 0); stageB(0, 1, 0);
  stageA(1, 0, 1); stageA(1, 1, 1); stageB(1, 0, 1); stageB(1, 1, 1);
  VMCNT8();
  BARRIER();

  for (int t = 0; t < nk; t += 2) {
    const bool first = (t == 0);
    const bool pf2 = (t + 2 < nk);
    const bool pf3 = (t + 3 < nk);
    // ======== tile t (buf0) ========
#pragma unroll
    for (int i = 0; i < 4; ++i)
#pragma unroll
      for (int kk = 0; kk < 2; ++kk) af[i][kk] = ldA(0, i, kk);
#pragma unroll
    for (int j = 0; j < 2; ++j)
#pragma unroll
      for (int kk = 0; kk < 2; ++kk) bfr[j][kk] = ldB(0, j, kk);
    if (!first) stageA(1, 1, t + 1);
    BARRIER(); LGKM0();
    __builtin_amdgcn_s_setprio(1);
#pragma unroll
    for (int i = 0; i < 4; ++i)
#pragma unroll
      for (int j = 0; j < 2; ++j)
#pragma unroll
        for (int kk = 0; kk < 2; ++kk) acc[i][j] = MFMA16(af[i][kk], bfr[j][kk], acc[i][j]);
    __builtin_amdgcn_s_setprio(0);
    BARRIER();
#pragma unroll
    for (int j = 0; j < 2; ++j)
#pragma unroll
      for (int kk = 0; kk < 2; ++kk) bfr[2 + j][kk] = ldB(0, 2 + j, kk);
    BARRIER(); LGKM0();
    __builtin_amdgcn_s_setprio(1);
#pragma unroll
    for (int i = 0; i < 4; ++i)
#pragma unroll
      for (int j = 0; j < 2; ++j)
#pragma unroll
        for (int kk = 0; kk < 2; ++kk) acc[i][2 + j] = MFMA16(af[i][kk], bfr[2 + j][kk], acc[i][2 + j]);
    __builtin_amdgcn_s_setprio(0);
    BARRIER();
#pragma unroll
    for (int i = 0; i < 4; ++i)
#pragma unroll
      for (int kk = 0; kk < 2; ++kk) af[i][kk] = ldA(0, 4 + i, kk);
    if (pf2) stageB(0, 0, t + 2);
    BARRIER(); LGKM0();
    __builtin_amdgcn_s_setprio(1);
#pragma unroll
    for (int i = 0; i < 4; ++i)
#pragma unroll
      for (int j = 0; j < 2; ++j)
#pragma unroll
        for (int kk = 0; kk < 2; ++kk) acc[4 + i][2 + j] = MFMA16(af[i][kk], bfr[2 + j][kk], acc[4 + i][2 + j]);
    __builtin_amdgcn_s_setprio(0);
    BARRIER();
    if (pf2) stageA(0, 0, t + 2);
    BARRIER();
    __builtin_amdgcn_s_setprio(1);
#pragma unroll
    for (int i = 0; i < 4; ++i)
#pragma unroll
      for (int j = 0; j < 2; ++j)
#pragma unroll
        for (int kk = 0; kk < 2; ++kk) acc[4 + i][j] = MFMA16(af[i][kk], bfr[j][kk], acc[4 + i][j]);
    __builtin_amdgcn_s_setprio(0);
    if (pf2) { VMCNT4(); } else { VMCNT0(); }
    BARRIER();
    // ======== tile t+1 (buf1) ========
#pragma unroll
    for (int i = 0; i < 4; ++i)
#pragma unroll
      for (int kk = 0; kk < 2; ++kk) af[i][kk] = ldA(1, i, kk);
#pragma unroll
    for (int j = 0; j < 2; ++j)
#pragma unroll
      for (int kk = 0; kk < 2; ++kk) bfr[j][kk] = ldB(1, j, kk);
    if (pf2) stageB(0, 1, t + 2);
    BARRIER(); LGKM0();
    __builtin_amdgcn_s_setprio(1);
#pragma unroll
    for (int i = 0; i < 4; ++i)
#pragma unroll
      for (int j = 0; j < 2; ++j)
#pragma unroll
        for (int kk = 0; kk < 2; ++kk) acc[i][j] = MFMA16(af[i][kk], bfr[j][kk], acc[i][j]);
    __builtin_amdgcn_s_setprio(0);
    BARRIER();
#pragma unroll
    for (int j = 0; j < 2; ++j)
#pragma unroll
      for (int kk = 0; kk < 2; ++kk) bfr[2 + j][kk] = ldB(1, 2 + j, kk);
    if (pf2) stageA(0, 1, t + 2);
    BARRIER(); LGKM0();
    __builtin_amdgcn_s_setprio(1);
#pragma unroll
    for (int i = 0; i < 4; ++i)
#pragma unroll
      for (int j = 0; j < 2; ++j)
#pragma unroll
        for (int kk = 0; kk < 2; ++kk) acc[i][2 + j] = MFMA16(af[i][kk], bfr[2 + j][kk], acc[i][2 + j]);
    __builtin_amdgcn_s_setprio(0);
    BARRIER();
#pragma unroll
    for (int i = 0; i < 4; ++i)
#pragma unroll
      for (int kk = 0; kk < 2; ++kk) af[i][kk] = ldA(1, 4 + i, kk);
    if (pf3) stageB(1, 0, t + 3);
    BARRIER(); LGKM0();
    __builtin_amdgcn_s_setprio(1);
#pragma unroll
    for (int i = 0; i < 4; ++i)
#pragma unroll
      for (int j = 0; j < 2; ++j)
#pragma unroll
        for (int kk = 0; kk < 2; ++kk) acc[4 + i][2 + j] = MFMA16(af[i][kk], bfr[2 + j][kk], acc[4 + i][2 + j]);
    __builtin_amdgcn_s_setprio(0);
    BARRIER();
    if (pf3) { stageB(1, 1, t + 3); stageA(1, 0, t + 3); }
    BARRIER();
    __builtin_amdgcn_s_setprio(1);
#pragma unroll
    for (int i = 0; i < 4; ++i)
#pragma unroll
      for (int j = 0; j < 2; ++j)
#pragma unroll
        for (int kk = 0; kk < 2; ++kk) acc[4 + i][j] = MFMA16(af[i][kk], bfr[j][kk], acc[4 + i][j]);
    __builtin_amdgcn_s_setprio(0);
    if (pf2) { VMCNT6(); } else { VMCNT0(); }
    BARRIER();
  }

#pragma unroll
  for (int mi = 0; mi < 8; ++mi)
#pragma unroll
    for (int ni = 0; ni < 4; ++ni)
#pragma unroll
      for (int p = 0; p < 4; ++p) {
        const int rr = row0 + wm * 128 + mi * 16 + 4 * g + p;
        const int cc = col0 + wn * 64 + ni * 16 + r;
        const float v = acc[mi][ni][p] + bias[cc];
        if (OUT_BF16) Cb[(size_t)rr * N + cc] = (bf16_t)v;
        else          Cf[(size_t)rr * N + cc] = v;
      }
}

// ---------------- flash attention + trailing Wout-transpose blocks ----------------
// 3 blocks/CU (LDS 53,248 B x 3 = 159,744 <= 160 KB): all 640 attn blocks co-resident,
// wtrans backfill starts as soon as any attn block retires.
__global__ __launch_bounds__(256, 3) void attn(const bf16_t* __restrict__ Q,
                                               const bf16_t* __restrict__ Kg,
                                               const bf16_t* __restrict__ Vt,
                                               bf16_t* __restrict__ O,
                                               const float* __restrict__ Wout,
                                               bf16_t* __restrict__ WOT) {
  __shared__ bf16_t k_lds[64 * HD];
  __shared__ bf16_t v_lds[144 * 64];
  __shared__ bf16_t p_lds[4][2][16 * 72];
  const int tid = threadIdx.x, wid = tid >> 6, lane = tid & 63;
  const int g = lane >> 4, r = lane & 15;
  const int bid = blockIdx.x;
  if (bid >= 640) {
    bf16_t* t = k_lds;
    const int b2 = bid - 640;
    const int k0 = (b2 % 80) * 64, n0 = (b2 / 80) * 64;
    const int tn = tid & 15, tk = tid >> 4;
    f32x4 v[4];
#pragma unroll
    for (int jj = 0; jj < 4; ++jj)
      v[jj] = *(const f32x4*)(Wout + (size_t)(k0 + 4 * tk + jj) * DIMC + n0 + 4 * tn);
#pragma unroll
    for (int j = 0; j < 4; ++j) {
      bf16x4 o;
#pragma unroll
      for (int jj = 0; jj < 4; ++jj) o[jj] = (bf16_t)v[jj][j];
      *(bf16x4*)&t[(4 * tn + j) * 68 + 4 * tk] = o;
    }
    __syncthreads();
#pragma unroll
    for (int i = 0; i < 2; ++i) {
      int c = i * 256 + tid, rn = c >> 3, ck = (c & 7) * 8;
      bf16x8 o = *(const bf16x8*)&t[rn * 68 + ck];
      *(bf16x8*)(WOT + (size_t)(n0 + rn) * DIMC + k0 + ck) = o;
    }
    return;
  }
  const int grp = bid & 7, inner = bid >> 3;
  const int h = (inner >> 4) * 8 + grp;
  const int q0 = (inner & 15) * 128 + wid * 32;
  bf16x8 qf[2][4];
#pragma unroll
  for (int rg = 0; rg < 2; ++rg) {
    const bf16_t* qrow = Q + ((size_t)h * L_C + q0 + rg * 16 + r) * HD;
#pragma unroll
    for (int ks = 0; ks < 4; ++ks) qf[rg][ks] = *(const bf16x8*)(qrow + ks * 32 + g * 8);
  }
  f32x4 oacc[2][9] = {};
  const float scale2 = 0.08838834764831845f * 1.4426950408889634f;

  for (int i = tid; i < 128; i += 256) {
    const int row = 128 + (i >> 3), cb = i & 7;
    bf16x8 cv;
#pragma unroll
    for (int j = 0; j < 8; ++j) cv[j] = (bf16_t)((row == 128) ? 1.f : 0.f);
    *(bf16x8*)((char*)v_lds + row * 128 + ((cb * 16) ^ ((row & 7) << 4))) = cv;
  }

  bf16x8 kreg[4], vreg[4];
  auto load_kv = [&](int kv0) {
#pragma unroll
    for (int i = 0; i < 4; ++i) {
      const int c = i * 256 + tid;
      const int krow = c >> 4, kcb = c & 15;
      kreg[i] = *(const bf16x8*)(Kg + ((size_t)h * L_C + kv0 + krow) * HD + kcb * 8);
      const int vrow = c >> 3, vcb = c & 7;
      vreg[i] = *(const bf16x8*)(Vt + ((size_t)h * HD + vrow) * L_C + kv0 + vcb * 8);
    }
  };
  load_kv(0);

  for (int kv0 = 0; kv0 < L_C; kv0 += 64) {
    __syncthreads();
#pragma unroll
    for (int i = 0; i < 4; ++i) {
      const int c = i * 256 + tid;
      const int krow = c >> 4, kcb = c & 15;
      *(bf16x8*)((char*)k_lds + krow * 256 + ((kcb * 16) ^ ((krow & 7) << 4))) = kreg[i];
      const int vrow = c >> 3, vcb = c & 7;
      *(bf16x8*)((char*)v_lds + vrow * 128 + ((vcb * 16) ^ ((vrow & 7) << 4))) = vreg[i];
    }
    if (kv0 + 64 < L_C) load_kv(kv0 + 64);
    __syncthreads();

    float pv[2][4][4];
    __builtin_amdgcn_s_setprio(1);
#pragma unroll
    for (int nf = 0; nf < 4; ++nf) {
      f32x4 s0 = {0.f, 0.f, 0.f, 0.f}, s1 = {0.f, 0.f, 0.f, 0.f};
      const int key = nf * 16 + r;
#pragma unroll
      for (int ks = 0; ks < 4; ++ks) {
        bf16x8 kf = *(const bf16x8*)((const char*)k_lds + key * 256 +
                                     ((ks * 64 + g * 16) ^ ((key & 7) << 4)));
        s0 = MFMA16(qf[0][ks], kf, s0);
        s1 = MFMA16(qf[1][ks], kf, s1);
      }
#pragma unroll
      for (int p = 0; p < 4; ++p) { pv[0][nf][p] = s0[p] * scale2; pv[1][nf][p] = s1[p] * scale2; }
    }
    __builtin_amdgcn_s_setprio(0);
#pragma unroll
    for (int rg = 0; rg < 2; ++rg)
#pragma unroll
      for (int nf = 0; nf < 4; ++nf)
#pragma unroll
        for (int p = 0; p < 4; ++p)
          p_lds[wid][rg][(4 * g + p) * 72 + nf * 16 + r] = (bf16_t)exp2f(pv[rg][nf][p]);
    bf16x8 pf0[2], pf1[2];
#pragma unroll
    for (int rg = 0; rg < 2; ++rg) {
      pf0[rg] = *(const bf16x8*)&p_lds[wid][rg][r * 72 + 8 * g];
      pf1[rg] = *(const bf16x8*)&p_lds[wid][rg][r * 72 + 32 + 8 * g];
    }
    __builtin_amdgcn_s_setprio(1);
#pragma unroll
    for (int nf = 0; nf < 9; ++nf) {
      const int d = nf * 16 + r;
      bf16x8 vf0 = *(const bf16x8*)((const char*)v_lds + d * 128 +
                                    ((g * 16) ^ ((d & 7) << 4)));
      bf16x8 vf1 = *(const bf16x8*)((const char*)v_lds + d * 128 +
                                    ((64 + g * 16) ^ ((d & 7) << 4)));
#pragma unroll
      for (int rg = 0; rg < 2; ++rg) {
        oacc[rg][nf] = MFMA16(pf0[rg], vf0, oacc[rg][nf]);
        oacc[rg][nf] = MFMA16(pf1[rg], vf1, oacc[rg][nf]);
      }
    }
    __builtin_amdgcn_s_setprio(0);
  }
#pragma unroll
  for (int rg = 0; rg < 2; ++rg)
#pragma unroll
    for (int p = 0; p < 4; ++p) {
      const float l = __shfl(oacc[rg][8][p], lane & 48, 64);
      const float inv = 1.f / l;
      const int rowg = q0 + rg * 16 + 4 * g + p;
#pragma unroll
      for (int nf = 0; nf < 8; ++nf) {
        const int d = nf * 16 + r;
        O[(size_t)rowg * DIMC + h * HD + d] = (bf16_t)(oacc[rg][nf][p] * inv);
      }
    }
}

// ---------------- launch ----------------
extern "C" void kernel_launch(void* const* d_in, const int* in_sizes, int n_in,
                              void* d_out, int out_size, void* d_ws, size_t ws_size,
                              hipStream_t stream) {
  const float* hidden = (const float*)d_in[0];
  const float* fcos   = (const float*)d_in[1];
  const float* fsin   = (const float*)d_in[2];
  const float* Wqkv   = (const float*)d_in[3];
  const float* bqkv   = (const float*)d_in[4];
  const float* wnq    = (const float*)d_in[5];
  const float* wnk    = (const float*)d_in[6];
  const float* Wout   = (const float*)d_in[7];
  const float* bout   = (const float*)d_in[8];
  float* out = (float*)d_out;

  char* ws = (char*)d_ws;
  size_t off = 0;
  auto alloc = [&](size_t bytes) {
    void* p = ws + off;
    off += (bytes + 255) & ~(size_t)255;
    return p;
  };
  bf16_t* X   = (bf16_t*)alloc((size_t)L_C * DIMC * 2);
  bf16_t* WQT = (bf16_t*)alloc((size_t)3 * DIMC * DIMC * 2);
  bf16_t* WOT = (bf16_t*)alloc((size_t)DIMC * DIMC * 2);
  bf16_t* QKV = (bf16_t*)alloc((size_t)L_C * 3 * DIMC * 2);
  bf16_t* Qb  = (bf16_t*)alloc((size_t)L_C * DIMC * 2);
  bf16_t* Kb  = (bf16_t*)alloc((size_t)L_C * DIMC * 2);
  bf16_t* VT  = (bf16_t*)alloc((size_t)L_C * DIMC * 2);
  bf16_t* Ob  = X;  // X dead after gemm1; reuse for attention output

  prep_all<<<19200 + 2048, 256, 0, stream>>>(hidden, X, Wqkv, WQT);
  gemm8<1, DIMC><<<dim3(L_C / 256, 3 * DIMC / 256), 512, 0, stream>>>(
      X, WQT, bqkv, QKV, nullptr, L_C, 3 * DIMC);
  post_qkv<<<2048 + 1280, 256, 0, stream>>>(QKV, wnq, wnk, fcos, fsin, Qb, Kb, VT);
  attn<<<640 + 6400, 256, 0, stream>>>(Qb, Kb, VT, Ob, Wout, WOT);
  gemm8<0, DIMC><<<dim3(L_C / 256, DIMC / 256), 512, 0, stream>>>(
      Ob, WOT, bout, nullptr, out, L_C, DIMC);
}

// Round 15
// 676.500 us; speedup vs baseline: 1.3949x; 1.3949x over previous
//
#include <hip/hip_runtime.h>
#include <cstdint>
#include <cstddef>

#define L_C   2048
#define DIMC  5120
#define HD    128
#define NHEADS 40

typedef __bf16 bf16_t;
typedef __bf16 bf16x8 __attribute__((ext_vector_type(8)));
typedef __bf16 bf16x4 __attribute__((ext_vector_type(4)));
typedef float  f32x4  __attribute__((ext_vector_type(4)));

#define MFMA16(A,B,C) __builtin_amdgcn_mfma_f32_16x16x32_bf16((A),(B),(C),0,0,0)
#define BARRIER() __builtin_amdgcn_s_barrier()
#define LGKM0()  asm volatile("s_waitcnt lgkmcnt(0)" ::: "memory")
#define VMCNT0() asm volatile("s_waitcnt vmcnt(0)" ::: "memory")
#define VMCNT4() asm volatile("s_waitcnt vmcnt(4)" ::: "memory")
#define VMCNT6() asm volatile("s_waitcnt vmcnt(6)" ::: "memory")
#define VMCNT8() asm volatile("s_waitcnt vmcnt(8)" ::: "memory")

__device__ __forceinline__ void gload16(const void* g, void* l) {
  __builtin_amdgcn_global_load_lds(
      (__attribute__((address_space(1))) void*)(void*)g,
      (__attribute__((address_space(3))) void*)l, 16, 0, 0);
}

// ======== prep: wtrans(Wqkv) [0,19200) | X convert [19200,21248) ========
__global__ __launch_bounds__(256) void prep_all(const float* __restrict__ hidden,
                                                bf16_t* __restrict__ X,
                                                const float* __restrict__ Wqkv,
                                                bf16_t* __restrict__ WQT) {
  __shared__ bf16_t t[64 * 68];
  const int tid = threadIdx.x;
  int bid = blockIdx.x;
  if (bid >= 19200) {
    size_t i = (size_t)(bid - 19200) * 256 + tid;
    const size_t n8 = (size_t)L_C * DIMC / 8;
    const size_t stride = (size_t)2048 * 256;
    for (; i < n8; i += stride) {
      f32x4 a = *(const f32x4*)(hidden + i * 8);
      f32x4 b = *(const f32x4*)(hidden + i * 8 + 4);
      bf16x8 o;
#pragma unroll
      for (int j = 0; j < 4; ++j) { o[j] = (bf16_t)a[j]; o[4 + j] = (bf16_t)b[j]; }
      *(bf16x8*)(X + i * 8) = o;
    }
    return;
  }
  const int K = DIMC, N = 3 * DIMC;
  const int k0 = (bid % 80) * 64, n0 = (bid / 80) * 64;
  const int tn = tid & 15, tk = tid >> 4;
  f32x4 v[4];
#pragma unroll
  for (int jj = 0; jj < 4; ++jj)
    v[jj] = *(const f32x4*)(Wqkv + (size_t)(k0 + 4 * tk + jj) * N + n0 + 4 * tn);
#pragma unroll
  for (int j = 0; j < 4; ++j) {
    bf16x4 o;
#pragma unroll
    for (int jj = 0; jj < 4; ++jj) o[jj] = (bf16_t)v[jj][j];
    *(bf16x4*)&t[(4 * tn + j) * 68 + 4 * tk] = o;
  }
  __syncthreads();
#pragma unroll
  for (int i = 0; i < 2; ++i) {
    int c = i * 256 + tid, rn = c >> 3, ck = (c & 7) * 8;
    bf16x8 o = *(const bf16x8*)&t[rn * 68 + ck];
    *(bf16x8*)(WQT + (size_t)(n0 + rn) * K + k0 + ck) = o;
  }
}

// ======== merged post-QKV: norm_rope [0,2048) | v_trans [2048,3328) ========
__global__ __launch_bounds__(256) void post_qkv(const bf16_t* __restrict__ qkv,
                                                const float* __restrict__ wq,
                                                const float* __restrict__ wk,
                                                const float* __restrict__ fcos,
                                                const float* __restrict__ fsin,
                                                bf16_t* __restrict__ Qo,
                                                bf16_t* __restrict__ Ko,
                                                bf16_t* __restrict__ Vt) {
  __shared__ __align__(16) char sbuf[20992];
  const int tid = threadIdx.x;
  if (blockIdx.x >= 2048) {
    bf16_t* t = (bf16_t*)sbuf;  // [128][68]
    const int idx = blockIdx.x - 2048;
    const int l0 = (idx & 31) * 64, h = idx >> 5;
    const int td = tid & 31, tl = tid >> 5;
#pragma unroll
    for (int it = 0; it < 2; ++it) {
      const int lq = tl + it * 8;
      bf16x4 v[4];
#pragma unroll
      for (int jj = 0; jj < 4; ++jj)
        v[jj] = *(const bf16x4*)(qkv + (size_t)(l0 + 4 * lq + jj) * (3 * DIMC) +
                                 2 * DIMC + h * HD + 4 * td);
#pragma unroll
      for (int j = 0; j < 4; ++j) {
        bf16x4 o;
#pragma unroll
        for (int jj = 0; jj < 4; ++jj) o[jj] = v[jj][j];
        *(bf16x4*)&t[(4 * td + j) * 68 + 4 * lq] = o;
      }
    }
    __syncthreads();
#pragma unroll
    for (int i = 0; i < 4; ++i) {
      int c = i * 256 + tid, d = c >> 3, cl = (c & 7) * 8;
      bf16x8 o = *(const bf16x8*)&t[d * 68 + cl];
      *(bf16x8*)(Vt + ((size_t)h * HD + d) * L_C + l0 + cl) = o;
    }
    return;
  }
  bf16_t* qs  = (bf16_t*)sbuf;
  bf16_t* ks_ = (bf16_t*)(sbuf + 10240);
  float*  red = (float*)(sbuf + 20480);
  const int l = blockIdx.x;
  const bf16_t* row = qkv + (size_t)l * (3 * DIMC);
  float sq = 0.f, sk = 0.f;
  for (int i = tid; i < DIMC / 8; i += 256) {
    bf16x8 a = *(const bf16x8*)(row + i * 8);
    bf16x8 b = *(const bf16x8*)(row + DIMC + i * 8);
    *(bf16x8*)&qs[i * 8] = a;
    *(bf16x8*)&ks_[i * 8] = b;
#pragma unroll
    for (int j = 0; j < 8; ++j) {
      float x = (float)a[j]; sq += x * x;
      float y = (float)b[j]; sk += y * y;
    }
  }
#pragma unroll
  for (int off = 32; off; off >>= 1) {
    sq += __shfl_xor(sq, off, 64);
    sk += __shfl_xor(sk, off, 64);
  }
  const int wid = tid >> 6, lane = tid & 63;
  if (!lane) { red[wid] = sq; red[4 + wid] = sk; }
  __syncthreads();
  sq = red[0] + red[1] + red[2] + red[3];
  sk = red[4] + red[5] + red[6] + red[7];
  const float rq = rsqrtf(sq * (1.f / DIMC) + 1e-6f);
  const float rk = rsqrtf(sk * (1.f / DIMC) + 1e-6f);
  for (int i = tid; i < DIMC / 8; i += 256) {
    const int j0 = i * 8, h = j0 >> 7, d0 = j0 & 127;
    bf16x8 a = *(const bf16x8*)&qs[j0];
    bf16x8 b = *(const bf16x8*)&ks_[j0];
    f32x4 cA = *(const f32x4*)(fcos + (size_t)l * HD + d0);
    f32x4 cB = *(const f32x4*)(fcos + (size_t)l * HD + d0 + 4);
    f32x4 sA = *(const f32x4*)(fsin + (size_t)l * HD + d0);
    f32x4 sB = *(const f32x4*)(fsin + (size_t)l * HD + d0 + 4);
    f32x4 wqA = *(const f32x4*)(wq + j0), wqB = *(const f32x4*)(wq + j0 + 4);
    f32x4 wkA = *(const f32x4*)(wk + j0), wkB = *(const f32x4*)(wk + j0 + 4);
    float cc[8], ss[8], qn[8], kn[8];
#pragma unroll
    for (int j = 0; j < 4; ++j) {
      cc[j] = cA[j]; cc[4 + j] = cB[j];
      ss[j] = sA[j]; ss[4 + j] = sB[j];
      qn[j] = (float)a[j] * rq * wqA[j];
      qn[4 + j] = (float)a[4 + j] * rq * wqB[j];
      kn[j] = (float)b[j] * rk * wkA[j];
      kn[4 + j] = (float)b[4 + j] * rk * wkB[j];
    }
    bf16x8 oq, ok;
#pragma unroll
    for (int p = 0; p < 4; ++p) {
      const float c = cc[2 * p], s = ss[2 * p + 1];
      oq[2 * p]     = (bf16_t)(qn[2 * p] * c - qn[2 * p + 1] * s);
      oq[2 * p + 1] = (bf16_t)(qn[2 * p] * s + qn[2 * p + 1] * c);
      ok[2 * p]     = (bf16_t)(kn[2 * p] * c - kn[2 * p + 1] * s);
      ok[2 * p + 1] = (bf16_t)(kn[2 * p] * s + kn[2 * p + 1] * c);
    }
    *(bf16x8*)(Qo + ((size_t)h * L_C + l) * HD + d0) = oq;
    *(bf16x8*)(Ko + ((size_t)h * L_C + l) * HD + d0) = ok;
  }
}

// ================= 256x256 GEMM, fine-interleaved 8-phase (round-7 verified) =================
template <int OUT_BF16, int K>
__global__ __launch_bounds__(512, 1) void gemm8(const bf16_t* __restrict__ A,
                                                const bf16_t* __restrict__ Bt,
                                                const float* __restrict__ bias,
                                                bf16_t* __restrict__ Cb,
                                                float* __restrict__ Cf,
                                                int M, int N) {
  __shared__ __align__(16) char smem[131072];
  const int tid = threadIdx.x;
  const int wid = tid >> 6, lane = tid & 63;
  const int g = lane >> 4, r = lane & 15;
  const int wm = wid >> 2, wn = wid & 3;
  const int nb = gridDim.x * gridDim.y;
  const int bid = blockIdx.y * gridDim.x + blockIdx.x;
  const int swz = (bid & 7) * (nb >> 3) + (bid >> 3);
  const int bm = swz % gridDim.x, bn = swz / gridDim.x;
  const int row0 = bm * 256, col0 = bn * 256;

  auto stageA = [&](int buf, int half, int kt) {
#pragma unroll
    for (int i = 0; i < 2; ++i) {
      const int idx = i * 512 + tid;
      const int rl = idx >> 3, c = idx & 7;
      gload16(A + (size_t)(row0 + half * 128 + rl) * K + kt * 64 + ((c ^ (rl & 7)) << 3),
              smem + buf * 65536 + half * 16384 + (i * 512 + wid * 64) * 16);
    }
  };
  auto stageB = [&](int buf, int half, int kt) {
#pragma unroll
    for (int i = 0; i < 2; ++i) {
      const int idx = i * 512 + tid;
      const int rl = idx >> 3, c = idx & 7;
      gload16(Bt + (size_t)(col0 + half * 128 + rl) * K + kt * 64 + ((c ^ (rl & 7)) << 3),
              smem + buf * 65536 + 32768 + half * 16384 + (i * 512 + wid * 64) * 16);
    }
  };
  auto ldA = [&](int buf, int mi, int kk) {
    const int rh = mi * 16 + r;
    return *(const bf16x8*)(smem + buf * 65536 + wm * 16384 + rh * 128 +
                            (((kk * 4 + g) ^ (r & 7)) << 4));
  };
  auto ldB = [&](int buf, int ni, int kk) {
    const int rh = (wn & 1) * 64 + ni * 16 + r;
    return *(const bf16x8*)(smem + buf * 65536 + 32768 + (wn >> 1) * 16384 + rh * 128 +
                            (((kk * 4 + g) ^ (r & 7)) << 4));
  };

  f32x4 acc[8][4] = {};
  bf16x8 af[4][2], bfr[4][2];
  constexpr int nk = K / 64;

  stageA(0, 0, 0); stageA(0, 1, 0); stageB(0, 0, 0); stageB(0, 1, 0);
  stageA(1, 0, 1); stageA(1, 1, 1); stageB(1, 0, 1); stageB(1, 1, 1);
  VMCNT8();
  BARRIER();

  for (int t = 0; t < nk; t += 2) {
    const bool first = (t == 0);
    const bool pf2 = (t + 2 < nk);
    const bool pf3 = (t + 3 < nk);
    // ======== tile t (buf0) ========
#pragma unroll
    for (int i = 0; i < 4; ++i)
#pragma unroll
      for (int kk = 0; kk < 2; ++kk) af[i][kk] = ldA(0, i, kk);
#pragma unroll
    for (int j = 0; j < 2; ++j)
#pragma unroll
      for (int kk = 0; kk < 2; ++kk) bfr[j][kk] = ldB(0, j, kk);
    if (!first) stageA(1, 1, t + 1);
    BARRIER(); LGKM0();
    __builtin_amdgcn_s_setprio(1);
#pragma unroll
    for (int i = 0; i < 4; ++i)
#pragma unroll
      for (int j = 0; j < 2; ++j)
#pragma unroll
        for (int kk = 0; kk < 2; ++kk) acc[i][j] = MFMA16(af[i][kk], bfr[j][kk], acc[i][j]);
    __builtin_amdgcn_s_setprio(0);
    BARRIER();
#pragma unroll
    for (int j = 0; j < 2; ++j)
#pragma unroll
      for (int kk = 0; kk < 2; ++kk) bfr[2 + j][kk] = ldB(0, 2 + j, kk);
    BARRIER(); LGKM0();
    __builtin_amdgcn_s_setprio(1);
#pragma unroll
    for (int i = 0; i < 4; ++i)
#pragma unroll
      for (int j = 0; j < 2; ++j)
#pragma unroll
        for (int kk = 0; kk < 2; ++kk) acc[i][2 + j] = MFMA16(af[i][kk], bfr[2 + j][kk], acc[i][2 + j]);
    __builtin_amdgcn_s_setprio(0);
    BARRIER();
#pragma unroll
    for (int i = 0; i < 4; ++i)
#pragma unroll
      for (int kk = 0; kk < 2; ++kk) af[i][kk] = ldA(0, 4 + i, kk);
    if (pf2) stageB(0, 0, t + 2);
    BARRIER(); LGKM0();
    __builtin_amdgcn_s_setprio(1);
#pragma unroll
    for (int i = 0; i < 4; ++i)
#pragma unroll
      for (int j = 0; j < 2; ++j)
#pragma unroll
        for (int kk = 0; kk < 2; ++kk) acc[4 + i][2 + j] = MFMA16(af[i][kk], bfr[2 + j][kk], acc[4 + i][2 + j]);
    __builtin_amdgcn_s_setprio(0);
    BARRIER();
    if (pf2) stageA(0, 0, t + 2);
    BARRIER();
    __builtin_amdgcn_s_setprio(1);
#pragma unroll
    for (int i = 0; i < 4; ++i)
#pragma unroll
      for (int j = 0; j < 2; ++j)
#pragma unroll
        for (int kk = 0; kk < 2; ++kk) acc[4 + i][j] = MFMA16(af[i][kk], bfr[j][kk], acc[4 + i][j]);
    __builtin_amdgcn_s_setprio(0);
    if (pf2) { VMCNT4(); } else { VMCNT0(); }
    BARRIER();
    // ======== tile t+1 (buf1) ========
#pragma unroll
    for (int i = 0; i < 4; ++i)
#pragma unroll
      for (int kk = 0; kk < 2; ++kk) af[i][kk] = ldA(1, i, kk);
#pragma unroll
    for (int j = 0; j < 2; ++j)
#pragma unroll
      for (int kk = 0; kk < 2; ++kk) bfr[j][kk] = ldB(1, j, kk);
    if (pf2) stageB(0, 1, t + 2);
    BARRIER(); LGKM0();
    __builtin_amdgcn_s_setprio(1);
#pragma unroll
    for (int i = 0; i < 4; ++i)
#pragma unroll
      for (int j = 0; j < 2; ++j)
#pragma unroll
        for (int kk = 0; kk < 2; ++kk) acc[i][j] = MFMA16(af[i][kk], bfr[j][kk], acc[i][j]);
    __builtin_amdgcn_s_setprio(0);
    BARRIER();
#pragma unroll
    for (int j = 0; j < 2; ++j)
#pragma unroll
      for (int kk = 0; kk < 2; ++kk) bfr[2 + j][kk] = ldB(1, 2 + j, kk);
    if (pf2) stageA(0, 1, t + 2);
    BARRIER(); LGKM0();
    __builtin_amdgcn_s_setprio(1);
#pragma unroll
    for (int i = 0; i < 4; ++i)
#pragma unroll
      for (int j = 0; j < 2; ++j)
#pragma unroll
        for (int kk = 0; kk < 2; ++kk) acc[i][2 + j] = MFMA16(af[i][kk], bfr[2 + j][kk], acc[i][2 + j]);
    __builtin_amdgcn_s_setprio(0);
    BARRIER();
#pragma unroll
    for (int i = 0; i < 4; ++i)
#pragma unroll
      for (int kk = 0; kk < 2; ++kk) af[i][kk] = ldA(1, 4 + i, kk);
    if (pf3) stageB(1, 0, t + 3);
    BARRIER(); LGKM0();
    __builtin_amdgcn_s_setprio(1);
#pragma unroll
    for (int i = 0; i < 4; ++i)
#pragma unroll
      for (int j = 0; j < 2; ++j)
#pragma unroll
        for (int kk = 0; kk < 2; ++kk) acc[4 + i][2 + j] = MFMA16(af[i][kk], bfr[2 + j][kk], acc[4 + i][2 + j]);
    __builtin_amdgcn_s_setprio(0);
    BARRIER();
    if (pf3) { stageB(1, 1, t + 3); stageA(1, 0, t + 3); }
    BARRIER();
    __builtin_amdgcn_s_setprio(1);
#pragma unroll
    for (int i = 0; i < 4; ++i)
#pragma unroll
      for (int j = 0; j < 2; ++j)
#pragma unroll
        for (int kk = 0; kk < 2; ++kk) acc[4 + i][j] = MFMA16(af[i][kk], bfr[j][kk], acc[4 + i][j]);
    __builtin_amdgcn_s_setprio(0);
    if (pf2) { VMCNT6(); } else { VMCNT0(); }
    BARRIER();
  }

#pragma unroll
  for (int mi = 0; mi < 8; ++mi)
#pragma unroll
    for (int ni = 0; ni < 4; ++ni)
#pragma unroll
      for (int p = 0; p < 4; ++p) {
        const int rr = row0 + wm * 128 + mi * 16 + 4 * g + p;
        const int cc = col0 + wn * 64 + ni * 16 + r;
        const float v = acc[mi][ni][p] + bias[cc];
        if (OUT_BF16) Cb[(size_t)rr * N + cc] = (bf16_t)v;
        else          Cf[(size_t)rr * N + cc] = v;
      }
}

// ---------------- flash attention + trailing Wout-transpose blocks ----------------
// attn role [0,640): NO-MAX softmax, l via ones-column PV. wtrans role [640,7040).
// __launch_bounds__(256,2): 2 blocks/CU — (256,3) caps VGPR at 84 and SPILLS (round-14).
__global__ __launch_bounds__(256, 2) void attn(const bf16_t* __restrict__ Q,
                                               const bf16_t* __restrict__ Kg,
                                               const bf16_t* __restrict__ Vt,
                                               bf16_t* __restrict__ O,
                                               const float* __restrict__ Wout,
                                               bf16_t* __restrict__ WOT) {
  __shared__ bf16_t k_lds[64 * HD];
  __shared__ bf16_t v_lds[144 * 64];
  __shared__ bf16_t p_lds[4][2][16 * 72];
  const int tid = threadIdx.x, wid = tid >> 6, lane = tid & 63;
  const int g = lane >> 4, r = lane & 15;
  const int bid = blockIdx.x;
  if (bid >= 640) {
    bf16_t* t = k_lds;
    const int b2 = bid - 640;
    const int k0 = (b2 % 80) * 64, n0 = (b2 / 80) * 64;
    const int tn = tid & 15, tk = tid >> 4;
    f32x4 v[4];
#pragma unroll
    for (int jj = 0; jj < 4; ++jj)
      v[jj] = *(const f32x4*)(Wout + (size_t)(k0 + 4 * tk + jj) * DIMC + n0 + 4 * tn);
#pragma unroll
    for (int j = 0; j < 4; ++j) {
      bf16x4 o;
#pragma unroll
      for (int jj = 0; jj < 4; ++jj) o[jj] = (bf16_t)v[jj][j];
      *(bf16x4*)&t[(4 * tn + j) * 68 + 4 * tk] = o;
    }
    __syncthreads();
#pragma unroll
    for (int i = 0; i < 2; ++i) {
      int c = i * 256 + tid, rn = c >> 3, ck = (c & 7) * 8;
      bf16x8 o = *(const bf16x8*)&t[rn * 68 + ck];
      *(bf16x8*)(WOT + (size_t)(n0 + rn) * DIMC + k0 + ck) = o;
    }
    return;
  }
  const int grp = bid & 7, inner = bid >> 3;
  const int h = (inner >> 4) * 8 + grp;
  const int q0 = (inner & 15) * 128 + wid * 32;
  bf16x8 qf[2][4];
#pragma unroll
  for (int rg = 0; rg < 2; ++rg) {
    const bf16_t* qrow = Q + ((size_t)h * L_C + q0 + rg * 16 + r) * HD;
#pragma unroll
    for (int ks = 0; ks < 4; ++ks) qf[rg][ks] = *(const bf16x8*)(qrow + ks * 32 + g * 8);
  }
  f32x4 oacc[2][9] = {};
  const float scale2 = 0.08838834764831845f * 1.4426950408889634f;

  for (int i = tid; i < 128; i += 256) {
    const int row = 128 + (i >> 3), cb = i & 7;
    bf16x8 cv;
#pragma unroll
    for (int j = 0; j < 8; ++j) cv[j] = (bf16_t)((row == 128) ? 1.f : 0.f);
    *(bf16x8*)((char*)v_lds + row * 128 + ((cb * 16) ^ ((row & 7) << 4))) = cv;
  }

  bf16x8 kreg[4], vreg[4];
  auto load_kv = [&](int kv0) {
#pragma unroll
    for (int i = 0; i < 4; ++i) {
      const int c = i * 256 + tid;
      const int krow = c >> 4, kcb = c & 15;
      kreg[i] = *(const bf16x8*)(Kg + ((size_t)h * L_C + kv0 + krow) * HD + kcb * 8);
      const int vrow = c >> 3, vcb = c & 7;
      vreg[i] = *(const bf16x8*)(Vt + ((size_t)h * HD + vrow) * L_C + kv0 + vcb * 8);
    }
  };
  load_kv(0);

  for (int kv0 = 0; kv0 < L_C; kv0 += 64) {
    __syncthreads();
#pragma unroll
    for (int i = 0; i < 4; ++i) {
      const int c = i * 256 + tid;
      const int krow = c >> 4, kcb = c & 15;
      *(bf16x8*)((char*)k_lds + krow * 256 + ((kcb * 16) ^ ((krow & 7) << 4))) = kreg[i];
      const int vrow = c >> 3, vcb = c & 7;
      *(bf16x8*)((char*)v_lds + vrow * 128 + ((vcb * 16) ^ ((vrow & 7) << 4))) = vreg[i];
    }
    if (kv0 + 64 < L_C) load_kv(kv0 + 64);
    __syncthreads();

    float pv[2][4][4];
    __builtin_amdgcn_s_setprio(1);
#pragma unroll
    for (int nf = 0; nf < 4; ++nf) {
      f32x4 s0 = {0.f, 0.f, 0.f, 0.f}, s1 = {0.f, 0.f, 0.f, 0.f};
      const int key = nf * 16 + r;
#pragma unroll
      for (int ks = 0; ks < 4; ++ks) {
        bf16x8 kf = *(const bf16x8*)((const char*)k_lds + key * 256 +
                                     ((ks * 64 + g * 16) ^ ((key & 7) << 4)));
        s0 = MFMA16(qf[0][ks], kf, s0);
        s1 = MFMA16(qf[1][ks], kf, s1);
      }
#pragma unroll
      for (int p = 0; p < 4; ++p) { pv[0][nf][p] = s0[p] * scale2; pv[1][nf][p] = s1[p] * scale2; }
    }
    __builtin_amdgcn_s_setprio(0);
#pragma unroll
    for (int rg = 0; rg < 2; ++rg)
#pragma unroll
      for (int nf = 0; nf < 4; ++nf)
#pragma unroll
        for (int p = 0; p < 4; ++p)
          p_lds[wid][rg][(4 * g + p) * 72 + nf * 16 + r] = (bf16_t)exp2f(pv[rg][nf][p]);
    bf16x8 pf0[2], pf1[2];
#pragma unroll
    for (int rg = 0; rg < 2; ++rg) {
      pf0[rg] = *(const bf16x8*)&p_lds[wid][rg][r * 72 + 8 * g];
      pf1[rg] = *(const bf16x8*)&p_lds[wid][rg][r * 72 + 32 + 8 * g];
    }
    __builtin_amdgcn_s_setprio(1);
#pragma unroll
    for (int nf = 0; nf < 9; ++nf) {
      const int d = nf * 16 + r;
      bf16x8 vf0 = *(const bf16x8*)((const char*)v_lds + d * 128 +
                                    ((g * 16) ^ ((d & 7) << 4)));
      bf16x8 vf1 = *(const bf16x8*)((const char*)v_lds + d * 128 +
                                    ((64 + g * 16) ^ ((d & 7) << 4)));
#pragma unroll
      for (int rg = 0; rg < 2; ++rg) {
        oacc[rg][nf] = MFMA16(pf0[rg], vf0, oacc[rg][nf]);
        oacc[rg][nf] = MFMA16(pf1[rg], vf1, oacc[rg][nf]);
      }
    }
    __builtin_amdgcn_s_setprio(0);
  }
#pragma unroll
  for (int rg = 0; rg < 2; ++rg)
#pragma unroll
    for (int p = 0; p < 4; ++p) {
      const float l = __shfl(oacc[rg][8][p], lane & 48, 64);
      const float inv = 1.f / l;
      const int rowg = q0 + rg * 16 + 4 * g + p;
#pragma unroll
      for (int nf = 0; nf < 8; ++nf) {
        const int d = nf * 16 + r;
        O[(size_t)rowg * DIMC + h * HD + d] = (bf16_t)(oacc[rg][nf][p] * inv);
      }
    }
}

// ---------------- launch ----------------
extern "C" void kernel_launch(void* const* d_in, const int* in_sizes, int n_in,
                              void* d_out, int out_size, void* d_ws, size_t ws_size,
                              hipStream_t stream) {
  const float* hidden = (const float*)d_in[0];
  const float* fcos   = (const float*)d_in[1];
  const float* fsin   = (const float*)d_in[2];
  const float* Wqkv   = (const float*)d_in[3];
  const float* bqkv   = (const float*)d_in[4];
  const float* wnq    = (const float*)d_in[5];
  const float* wnk    = (const float*)d_in[6];
  const float* Wout   = (const float*)d_in[7];
  const float* bout   = (const float*)d_in[8];
  float* out = (float*)d_out;

  char* ws = (char*)d_ws;
  size_t off = 0;
  auto alloc = [&](size_t bytes) {
    void* p = ws + off;
    off += (bytes + 255) & ~(size_t)255;
    return p;
  };
  bf16_t* X   = (bf16_t*)alloc((size_t)L_C * DIMC * 2);
  bf16_t* WQT = (bf16_t*)alloc((size_t)3 * DIMC * DIMC * 2);
  bf16_t* WOT = (bf16_t*)alloc((size_t)DIMC * DIMC * 2);
  bf16_t* QKV = (bf16_t*)alloc((size_t)L_C * 3 * DIMC * 2);
  bf16_t* Qb  = (bf16_t*)alloc((size_t)L_C * DIMC * 2);
  bf16_t* Kb  = (bf16_t*)alloc((size_t)L_C * DIMC * 2);
  bf16_t* VT  = (bf16_t*)alloc((size_t)L_C * DIMC * 2);
  bf16_t* Ob  = X;  // X dead after gemm1; reuse for attention output

  prep_all<<<19200 + 2048, 256, 0, stream>>>(hidden, X, Wqkv, WQT);
  gemm8<1, DIMC><<<dim3(L_C / 256, 3 * DIMC / 256), 512, 0, stream>>>(
      X, WQT, bqkv, QKV, nullptr, L_C, 3 * DIMC);
  post_qkv<<<2048 + 1280, 256, 0, stream>>>(QKV, wnq, wnk, fcos, fsin, Qb, Kb, VT);
  attn<<<640 + 6400, 256, 0, stream>>>(Qb, Kb, VT, Ob, Wout, WOT);
  gemm8<0, DIMC><<<dim3(L_C / 256, DIMC / 256), 512, 0, stream>>>(
      Ob, WOT, bout, nullptr, out, L_C, DIMC);
}